// Round 2
// baseline (362.145 us; speedup 1.0000x reference)
//
#include <hip/hip_runtime.h>
#include <hip/hip_bf16.h>
#include <cstdint>
#include <cstddef>

#define N_LEVELS   16
#define LOG2_T     19
#define TABLE_SIZE (1u << LOG2_T)
#define HASH_MASK  (TABLE_SIZE - 1u)
#define PRIME1     2654435761u

#define TPB 512
#define BT  128         // points per block

typedef __attribute__((ext_vector_type(8))) short short8;
typedef __attribute__((ext_vector_type(4))) float floatx4;
typedef __attribute__((ext_vector_type(2))) float f32x2;

// floor(16 * (2^(1/3))^l) in fp32 lands exactly on these integers
__device__ __constant__ float c_res[N_LEVELS] = {
    16.f, 20.f, 25.f, 32.f, 40.f, 50.f, 64.f, 80.f,
    101.f, 128.f, 161.f, 203.f, 256.f, 322.f, 406.f, 512.f
};

__device__ __forceinline__ unsigned short f2bf(float x) {
    union { float f; uint32_t u; } v; v.f = x;
    const uint32_t u = v.u;
    return (unsigned short)((u + 0x7fffu + ((u >> 16) & 1u)) >> 16);  // RNE
}

__device__ __forceinline__ uint32_t pk_bf16(float a, float b) {
#if __has_builtin(__builtin_amdgcn_cvt_pk_bf16_f32)
    typedef __attribute__((ext_vector_type(2))) __bf16 bf16x2;
    bf16x2 v = __builtin_amdgcn_cvt_pk_bf16_f32(a, b);
    uint32_t u; __builtin_memcpy(&u, &v, 4); return u;
#else
    return (uint32_t)f2bf(a) | ((uint32_t)f2bf(b) << 16);
#endif
}

// ---- XOR-swizzled LDS byte offsets (16B granules spread by row&7) ----
__device__ __forceinline__ int fswz(int row, int cb) {   // feat: 128 B/row
    return (row << 7) + (cb ^ ((row & 7) << 4));
}
__device__ __forceinline__ int hswz(int row, int cb) {   // h: 512 B/row
    return (row << 9) + (cb ^ ((row & 7) << 4));
}

// ---------------- weight packing into MFMA fragments ----------------
// Fragment for (tile, ktile): lane (q=l>>4, r=l&15) holds W[k = kt*32 + q*8 + j][col = tile*16 + r].
__global__ void pack_weights(const float* __restrict__ W0,
                             const float* __restrict__ W1,
                             const float* __restrict__ W2,
                             unsigned short* __restrict__ ws)
{
    const int f = blockIdx.x;       // 0..167
    const int lane = threadIdx.x;   // 0..63
    const int q = lane >> 4, r = lane & 15;
    int layer, kt, nt;
    if (f < 32)       { layer = 0; kt = f >> 4;        nt = f & 15; }
    else if (f < 160) { layer = 1; kt = (f - 32) >> 4; nt = (f - 32) & 15; }
    else              { layer = 2; kt = f - 160;       nt = 0; }
    unsigned short vals[8];
    #pragma unroll
    for (int j = 0; j < 8; ++j) {
        const int k = kt * 32 + q * 8 + j;
        const int n = nt * 16 + r;
        float v = 0.f;
        if (layer == 0) {
            // feat order: [enc0..enc31, x, y, zeros]; original W0 rows: [x, y, enc0..enc31]
            if (k < 32)       v = W0[(2 + k) * 256 + n];
            else if (k == 32) v = W0[0 * 256 + n];
            else if (k == 33) v = W0[1 * 256 + n];
        } else if (layer == 1) {
            v = W1[k * 256 + n];
        } else {
            if (n < 3) v = W2[k * 3 + n];
        }
        vals[j] = f2bf(v);
    }
    uint4 pk;
    pk.x = (uint32_t)vals[0] | ((uint32_t)vals[1] << 16);
    pk.y = (uint32_t)vals[2] | ((uint32_t)vals[3] << 16);
    pk.z = (uint32_t)vals[4] | ((uint32_t)vals[5] << 16);
    pk.w = (uint32_t)vals[6] | ((uint32_t)vals[7] << 16);
    *(uint4*)(ws + (size_t)f * 1024 + lane * 8) = pk;
}

// ---- phase-1 gather helper: 4 levels of one group, all 16 loads in flight ----
template<bool NT>
__device__ __forceinline__ void enc_gather(int g, float x, float y,
                                           const f32x2* __restrict__ emb2,
                                           float (&wxa)[4], float (&wya)[4],
                                           f32x2 (&e)[4][4])
{
    #pragma unroll
    for (int i = 0; i < 4; ++i) {
        const int l = 4 * g + i;
        const float res  = c_res[l];
        const float grid = 2.0f / res;             // IEEE div (matches ref)
        const float invg = res * 0.5f;             // exact
        const float tx = (x + 1.0f) / grid;        // IEEE div feeds floor -> exact cell match
        const float ty = (y + 1.0f) / grid;
        const int bx = (int)floorf(tx);
        const int by = (int)floorf(ty);
        const float vx = (float)bx * grid - 1.0f;
        const float vy = (float)by * grid - 1.0f;
        wxa[i] = (x - vx) * invg;
        wya[i] = (y - vy) * invg;
        const f32x2* tab = emb2 + (size_t)l * TABLE_SIZE;
        const uint32_t ux0 = (uint32_t)bx, ux1 = (uint32_t)(bx + 1);
        const uint32_t hy0 = (uint32_t)by * PRIME1;
        const uint32_t hy1 = (uint32_t)(by + 1) * PRIME1;
        const uint32_t i00 = (ux0 ^ hy0) & HASH_MASK;
        const uint32_t i01 = (ux0 ^ hy1) & HASH_MASK;
        const uint32_t i10 = (ux1 ^ hy0) & HASH_MASK;
        const uint32_t i11 = (ux1 ^ hy1) & HASH_MASK;
        if (NT) {   // fine levels: stream through, don't thrash L1/L2
            e[i][0] = __builtin_nontemporal_load(tab + i00);
            e[i][1] = __builtin_nontemporal_load(tab + i01);
            e[i][2] = __builtin_nontemporal_load(tab + i10);
            e[i][3] = __builtin_nontemporal_load(tab + i11);
        } else {    // coarse levels: keep cached (heavy cross-point reuse)
            e[i][0] = tab[i00];
            e[i][1] = tab[i01];
            e[i][2] = tab[i10];
            e[i][3] = tab[i11];
        }
    }
}

// ---------------- fused encoding + MLP ----------------
__global__ __launch_bounds__(TPB, 4)
void fused_ngp_mlp(const float* __restrict__ coord,
                   const float* __restrict__ emb,
                   const unsigned short* __restrict__ wpack,
                   const float* __restrict__ b0,
                   const float* __restrict__ b1,
                   const float* __restrict__ b2,
                   float* __restrict__ out, int npoints)
{
    // bf16 feature tile [BT][64] (XOR-swizzled rows): [enc0..31, x, y, 0-pad..63]
    __shared__ __attribute__((aligned(16))) unsigned char feat[BT * 128];   // 16 KB
    // bf16 hidden tile [BT][256] (XOR-swizzled rows): h0, then h1; [point][neuron]
    __shared__ __attribute__((aligned(16))) unsigned char h[BT * 512];      // 64 KB

    const int t = threadIdx.x;
    const int p0 = blockIdx.x * BT;
    const int wave = t >> 6;
    const int lane = t & 63;
    const int q = lane >> 4, r = lane & 15;

    // ---------- phase 1a: x,y + zero fill (bytes 64..127 of each feat row) ----------
    {
        const int p = t >> 2;          // 0..127
        const int sg = t & 3;
        const int gp = p0 + p;
        float x = 0.f, y = 0.f;
        if (gp < npoints) {
            x = coord[2 * gp + 0]; y = coord[2 * gp + 1];
            x = fminf(fmaxf(x, -1.f), 1.f);
            y = fminf(fmaxf(y, -1.f), 1.f);
        }
        uint4 z = {0u, 0u, 0u, 0u};
        if (sg == 0) z.x = pk_bf16(x, y);
        *(uint4*)(feat + fswz(p, 64 + 16 * sg)) = z;
    }

    // ---------- phase 1b: hash-grid gathers, wave-uniform level group ----------
    {
        const int g = wave & 3;                  // level group (wave-uniform)
        const int p = ((wave >> 2) << 6) + lane; // 0..127
        const int gp = p0 + p;
        float x = 0.f, y = 0.f;
        if (gp < npoints) {
            x = coord[2 * gp + 0]; y = coord[2 * gp + 1];
            x = fminf(fmaxf(x, -1.f), 1.f);
            y = fminf(fmaxf(y, -1.f), 1.f);
        }
        float wxa[4], wya[4];
        f32x2 e[4][4];
        const f32x2* emb2 = (const f32x2*)emb;
        if (g >= 2) enc_gather<true >(g, x, y, emb2, wxa, wya, e);
        else        enc_gather<false>(g, x, y, emb2, wxa, wya, e);
        uint32_t vv[4];
        #pragma unroll
        for (int i = 0; i < 4; ++i) {
            const float wx = wxa[i], wy = wya[i];
            const float owx = 1.f - wx, owy = 1.f - wy;
            const float f0 = (e[i][0].x * owx + e[i][2].x * wx) * owy
                           + (e[i][1].x * owx + e[i][3].x * wx) * wy;
            const float f1 = (e[i][0].y * owx + e[i][2].y * wx) * owy
                           + (e[i][1].y * owx + e[i][3].y * wx) * wy;
            vv[i] = pk_bf16(f0, f1);
        }
        uint4 v; v.x = vv[0]; v.y = vv[1]; v.z = vv[2]; v.w = vv[3];
        *(uint4*)(feat + fswz(p, 16 * g)) = v;   // one 16 B write: levels 4g..4g+3
    }
    __syncthreads();

    const unsigned short* w0p = wpack;
    const unsigned short* w1p = wpack + 32 * 1024;
    const unsigned short* w2p = wpack + 160 * 1024;

    // ---------- phase 2: layer 0 (K=64 padded), W^T x feat^T -> h0[point][neuron] ----------
    {
        floatx4 acc[2][8];   // [mti (neuron tile)][nt (point tile)]
        #pragma unroll
        for (int mti = 0; mti < 2; ++mti)
            #pragma unroll
            for (int nt = 0; nt < 8; ++nt)
                acc[mti][nt] = floatx4{0.f, 0.f, 0.f, 0.f};
        #pragma unroll
        for (int kt = 0; kt < 2; ++kt) {
            short8 a[2];
            #pragma unroll
            for (int mti = 0; mti < 2; ++mti)
                a[mti] = *(const short8*)(w0p + (size_t)(kt * 16 + wave * 2 + mti) * 1024 + lane * 8);
            #pragma unroll
            for (int nt = 0; nt < 8; ++nt) {
                const short8 b = *(const short8*)(feat + fswz(16 * nt + r, 64 * kt + 16 * q));
                #pragma unroll
                for (int mti = 0; mti < 2; ++mti)
                    acc[mti][nt] = __builtin_amdgcn_mfma_f32_16x16x32_bf16(a[mti], b, acc[mti][nt], 0, 0, 0);
            }
        }
        // C[m=neuron=(wave*2+mti)*16+4q+reg][n=point=16nt+r]
        #pragma unroll
        for (int mti = 0; mti < 2; ++mti) {
            const int col = (wave * 2 + mti) * 16 + 4 * q;
            const float4 bias = *(const float4*)&b0[col];
            #pragma unroll
            for (int nt = 0; nt < 8; ++nt) {
                const floatx4 a = acc[mti][nt];
                uint2 v;
                v.x = pk_bf16(fmaxf(a[0] + bias.x, 0.f), fmaxf(a[1] + bias.y, 0.f));
                v.y = pk_bf16(fmaxf(a[2] + bias.z, 0.f), fmaxf(a[3] + bias.w, 0.f));
                *(uint2*)(h + hswz(16 * nt + r, 2 * col)) = v;
            }
        }
    }
    __syncthreads();

    // ---------- phase 3: layer 1 (256 -> 256) ----------
    {
        floatx4 acc[2][8];
        #pragma unroll
        for (int mti = 0; mti < 2; ++mti)
            #pragma unroll
            for (int nt = 0; nt < 8; ++nt)
                acc[mti][nt] = floatx4{0.f, 0.f, 0.f, 0.f};
        #pragma unroll 2
        for (int kt = 0; kt < 8; ++kt) {
            short8 a[2];
            #pragma unroll
            for (int mti = 0; mti < 2; ++mti)
                a[mti] = *(const short8*)(w1p + (size_t)(kt * 16 + wave * 2 + mti) * 1024 + lane * 8);
            #pragma unroll
            for (int nt = 0; nt < 8; ++nt) {
                const short8 b = *(const short8*)(h + hswz(16 * nt + r, 64 * kt + 16 * q));
                #pragma unroll
                for (int mti = 0; mti < 2; ++mti)
                    acc[mti][nt] = __builtin_amdgcn_mfma_f32_16x16x32_bf16(a[mti], b, acc[mti][nt], 0, 0, 0);
            }
        }
        __syncthreads();   // all reads of h0 done before overwrite
        #pragma unroll
        for (int mti = 0; mti < 2; ++mti) {
            const int col = (wave * 2 + mti) * 16 + 4 * q;
            const float4 bias = *(const float4*)&b1[col];
            #pragma unroll
            for (int nt = 0; nt < 8; ++nt) {
                const floatx4 a = acc[mti][nt];
                uint2 v;
                v.x = pk_bf16(fmaxf(a[0] + bias.x, 0.f), fmaxf(a[1] + bias.y, 0.f));
                v.y = pk_bf16(fmaxf(a[2] + bias.z, 0.f), fmaxf(a[3] + bias.w, 0.f));
                *(uint2*)(h + hswz(16 * nt + r, 2 * col)) = v;
            }
        }
    }
    __syncthreads();

    // ---------- phase 4: layer 2 (256 -> 3), sigmoid, store (all 8 waves) ----------
    {
        floatx4 acc = floatx4{0.f, 0.f, 0.f, 0.f};
        #pragma unroll
        for (int kt = 0; kt < 8; ++kt) {
            const short8 a = *(const short8*)(w2p + (size_t)kt * 1024 + lane * 8);
            const short8 b = *(const short8*)(h + hswz(16 * wave + r, 64 * kt + 16 * q));
            acc = __builtin_amdgcn_mfma_f32_16x16x32_bf16(a, b, acc, 0, 0, 0);
        }
        // C[m=4q+reg][n=16*wave+r]: only q==0, reg<3 are real outputs
        if (q == 0) {
            const int gp = p0 + 16 * wave + r;
            if (gp < npoints) {
                #pragma unroll
                for (int reg = 0; reg < 3; ++reg) {
                    const float s = acc[reg] + b2[reg];
                    out[(size_t)gp * 3 + reg] = 1.f / (1.f + expf(-s));
                }
            }
        }
    }
}

extern "C" void kernel_launch(void* const* d_in, const int* in_sizes, int n_in,
                              void* d_out, int out_size, void* d_ws, size_t ws_size,
                              hipStream_t stream) {
    const float* coord = (const float*)d_in[0];
    const float* emb   = (const float*)d_in[1];
    const float* W0    = (const float*)d_in[2];
    const float* b0    = (const float*)d_in[3];
    const float* W1    = (const float*)d_in[4];
    const float* b1    = (const float*)d_in[5];
    const float* W2    = (const float*)d_in[6];
    const float* b2    = (const float*)d_in[7];
    float* out = (float*)d_out;
    unsigned short* ws = (unsigned short*)d_ws;

    const int npoints = in_sizes[0] / 2;
    const int blocks  = (npoints + BT - 1) / BT;

    hipLaunchKernelGGL(pack_weights, dim3(168), dim3(64), 0, stream, W0, W1, W2, ws);
    hipLaunchKernelGGL(fused_ngp_mlp, dim3(blocks), dim3(TPB), 0, stream,
                       coord, emb, ws, b0, b1, b2, out, npoints);
}